// Round 16
// baseline (706.684 us; speedup 1.0000x reference)
//
#include <hip/hip_runtime.h>
#include <hip/hip_bf16.h>
#include <stdint.h>

typedef short bf16x8 __attribute__((ext_vector_type(8)));
typedef float f32x4 __attribute__((ext_vector_type(4)));

__device__ __forceinline__ float b2f(ushort u){ return __uint_as_float(((uint32_t)u)<<16); }
__device__ __forceinline__ ushort f2b(float f){
  uint32_t u = __float_as_uint(f);
  u += 0x7fffu + ((u>>16)&1u);
  return (ushort)(u>>16);
}
__device__ __forceinline__ float hswish(float x){ return x*fminf(fmaxf(x+3.f,0.f),6.f)*(1.f/6.f); }

// async global->LDS 16B (dest = wave-uniform base + lane*16)
__device__ __forceinline__ void gll16(const void* g, void* l){
  __builtin_amdgcn_global_load_lds((const __attribute__((address_space(1))) void*)g,
                                   (__attribute__((address_space(3))) void*)l, 16, 0, 0);
}

// ---------- init: zero stats accumulators + convert weights to bf16 ----------
__global__ void init_kernel(const float* __restrict__ Wdc, const float* __restrict__ Wkv,
                            ushort* __restrict__ Wdc_b, ushort* __restrict__ Wkv_b,
                            float* __restrict__ zbase){
  int i = blockIdx.x*256 + threadIdx.x;
  if (i < 8192) zbase[i] = 0.f;
  for (int j=i; j<512*1024; j+=262144) Wdc_b[j] = f2b(Wdc[j]);
  for (int j=i; j<1536*512; j+=262144) Wkv_b[j] = f2b(Wkv[j]);
}

// ---------- transpose im_emd (B,C,N) f32 -> At[(b*N+n)][c] bf16 ----------
__global__ __launch_bounds__(256) void transpose_kernel(const float* __restrict__ im, ushort* __restrict__ At){
  __shared__ float tb[64][65];
  const int b = blockIdx.z, c0 = blockIdx.y*64, n0 = blockIdx.x*64;
  const int tid = threadIdx.x;
  const int cl = tid >> 2, q = tid & 3;
  #pragma unroll
  for (int it=0; it<4; ++it){
    int nn = q*4 + it*16;
    float4 v = *(const float4*)&im[((size_t)(b*1024 + c0 + cl))*9216 + n0 + nn];
    tb[cl][nn+0]=v.x; tb[cl][nn+1]=v.y; tb[cl][nn+2]=v.z; tb[cl][nn+3]=v.w;
  }
  __syncthreads();
  const int nr = tid >> 4, c4 = (tid & 15)*4;
  #pragma unroll
  for (int ps=0; ps<4; ++ps){
    int nn = nr + ps*16;
    ushort4 u;
    u.x = f2b(tb[c4+0][nn]); u.y = f2b(tb[c4+1][nn]);
    u.z = f2b(tb[c4+2][nn]); u.w = f2b(tb[c4+3][nn]);
    *(ushort4*)&At[((size_t)(b*9216 + n0 + nn))*1024 + c0 + c4] = u;
  }
}

// ---------- MFMA GEMM 128x128 block tile, 512 thr (8 waves, 2M x 4N, 64x32/wave) ----------
// Lower register footprint (acc[4][2] = 32 AGPR) to raise occupancy.
// SPLIT=0: C -> Cm[m][N].  SPLIT=1 (kv): K cols -> Kbuf[b][n][h][64], V cols -> Vt[b][h][dv][9216]
template<int SPLIT, int NT, int N, int K>
__global__ __launch_bounds__(512) void gemm_bt(
    const ushort* __restrict__ A, const ushort* __restrict__ Bm,
    ushort* __restrict__ Cm, ushort* __restrict__ Vt,
    float* __restrict__ sums, float* __restrict__ sqs)
{
  __shared__ __align__(16) ushort As[128*64];
  __shared__ __align__(16) ushort Bs[128*64];
  const int tid = threadIdx.x;
  const int l = tid & 63;
  const int w = tid >> 6;
  const int wm = w >> 2, wn = w & 3;      // 2M x 4N, per-wave 64x32
  const int chunk = gridDim.x >> 3;
  const int wg = (blockIdx.x & 7)*chunk + (blockIdx.x >> 3);
  const int tn = wg % NT, tm = wg / NT;
  const size_t n0 = (size_t)tn * 128;
  const size_t m0 = (size_t)tm * 128;
  const int lr = l & 15, lk = l >> 4;
  const int wbase = tid & ~63;

  // staging: 2 loads per thread per matrix (512 thr x 2 x 8 elem = 8192)
  const ushort* asrc[2]; const ushort* bsrc[2]; ushort* adst[2]; ushort* bdst[2];
  #pragma unroll
  for (int it=0; it<2; ++it){
    int idx = it*512 + tid;
    int row = idx >> 3, c8 = idx & 7;
    int sc8 = c8 ^ (row & 7);
    asrc[it] = A  + (m0+row)*K + sc8*8;
    bsrc[it] = Bm + (n0+row)*K + sc8*8;
    adst[it] = &As[(it*512 + wbase)*8];
    bdst[it] = &Bs[(it*512 + wbase)*8];
  }
  const int swz = (lr & 7) << 3;
  const ushort* ap0 = &As[(wm*64 + lr)*64 + ((lk*8) ^ swz)];
  const ushort* ap1 = &As[(wm*64 + lr)*64 + ((lk*8) ^ swz ^ 32)];
  const ushort* bp0 = &Bs[(wn*32 + lr)*64 + ((lk*8) ^ swz)];
  const ushort* bp1 = &Bs[(wn*32 + lr)*64 + ((lk*8) ^ swz ^ 32)];

  f32x4 acc[4][2];
  #pragma unroll
  for (int i=0;i<4;++i){ acc[i][0]=(f32x4){0.f,0.f,0.f,0.f}; acc[i][1]=(f32x4){0.f,0.f,0.f,0.f}; }

  #pragma unroll
  for (int kt = 0; kt < K; kt += 64) {
    #pragma unroll
    for (int it=0; it<2; ++it) {
      gll16(asrc[it] + kt, adst[it]);
      gll16(bsrc[it] + kt, bdst[it]);
    }
    __syncthreads();
    #pragma unroll
    for (int kk=0; kk<2; ++kk) {
      const ushort* ap = kk ? ap1 : ap0;
      const ushort* bp = kk ? bp1 : bp0;
      bf16x8 af[4], bfr[2];
      #pragma unroll
      for (int i=0;i<4;++i) af[i]  = *(const bf16x8*)(ap + i*1024);
      #pragma unroll
      for (int j=0;j<2;++j) bfr[j] = *(const bf16x8*)(bp + j*1024);
      #pragma unroll
      for (int i=0;i<4;++i)
        #pragma unroll
        for (int j=0;j<2;++j)
          acc[i][j] = __builtin_amdgcn_mfma_f32_16x16x32_bf16(af[i], bfr[j], acc[i][j], 0, 0, 0);
    }
    __syncthreads();
  }
  if constexpr (SPLIT==0){
    #pragma unroll
    for (int i=0;i<4;++i)
      #pragma unroll
      for (int j=0;j<2;++j)
        #pragma unroll
        for (int r=0;r<4;++r) {
          size_t row = m0 + wm*64 + i*16 + lk*4 + r;
          size_t col = n0 + wn*32 + j*16 + lr;
          Cm[row*N + col] = f2b(acc[i][j][r]);
        }
  } else {
    const int bq = (int)(m0/9216);
    const int nbase = (int)(m0 - (size_t)bq*9216);
    #pragma unroll
    for (int j=0;j<2;++j){
      int c = (int)n0 + wn*32 + j*16 + lr;
      int h = c/192, rcol = c - h*192;
      #pragma unroll
      for (int i=0;i<4;++i){
        int nrow = nbase + wm*64 + i*16 + lk*4;
        if (rcol < 64){
          ushort* kb = Cm + ((size_t)(bq*9216 + nrow))*512 + h*64 + rcol;
          #pragma unroll
          for (int r=0;r<4;++r) kb[(size_t)r*512] = f2b(acc[i][j][r]);
        } else {
          int dv = rcol - 64;
          ushort4 u;
          u.x=f2b(acc[i][j][0]); u.y=f2b(acc[i][j][1]);
          u.z=f2b(acc[i][j][2]); u.w=f2b(acc[i][j][3]);
          *(ushort4*)&Vt[((size_t)((bq*8+h)*128 + dv))*9216 + nrow] = u;
        }
      }
    }
  }
  #pragma unroll
  for (int j=0;j<2;++j){
    float cs=0.f, cq=0.f;
    #pragma unroll
    for (int i=0;i<4;++i)
      #pragma unroll
      for (int r=0;r<4;++r){ float v=acc[i][j][r]; cs+=v; cq+=v*v; }
    cs += __shfl_xor(cs,16); cs += __shfl_xor(cs,32);
    cq += __shfl_xor(cq,16); cq += __shfl_xor(cq,32);
    if (lk==0){
      int col = (int)n0 + wn*32 + j*16 + lr;
      atomicAdd(&sums[col], cs);
      atomicAdd(&sqs [col], cq);
    }
  }
}

// ---------- BN(inline finalize) + hardswish in place on y1 ----------
__global__ __launch_bounds__(256) void bn_hswish(ushort* __restrict__ y,
    const float* __restrict__ ssum, const float* __restrict__ ssq,
    const float* __restrict__ g, const float* __restrict__ bb)
{
  __shared__ float sc[512], sh[512];
  const float invn = 1.f/73728.f;
  for (int i=threadIdx.x;i<512;i+=256){
    float mu = ssum[i]*invn;
    float var = ssq[i]*invn - mu*mu;
    float k = g[i]*rsqrtf(var+1e-5f);
    sc[i]=k; sh[i]=bb[i]-mu*k;
  }
  __syncthreads();
  const size_t total = (size_t)73728*512/8;
  for (size_t idx = (size_t)blockIdx.x*256+threadIdx.x; idx < total; idx += (size_t)gridDim.x*256){
    uint4 u = *(uint4*)&y[idx*8];
    ushort* up = (ushort*)&u;
    int c0 = ((int)(idx & 63))*8;
    #pragma unroll
    for (int e=0;e<8;++e){
      float x = b2f(up[e])*sc[c0+e] + sh[c0+e];
      up[e] = f2b(hswish(x));
    }
    *(uint4*)&y[idx*8] = u;
  }
}

// ---------- q = text @ Wq^T (raw, f32), one text-row per block ----------
__global__ __launch_bounds__(256) void q_gemm(const float* __restrict__ text, const float* __restrict__ Wq, float* __restrict__ qraw)
{
  __shared__ __align__(16) float xr[512];
  const int t = blockIdx.x, tid = threadIdx.x;
  for (int i=tid;i<512;i+=256) xr[i] = text[t*512+i];
  __syncthreads();
  #pragma unroll
  for (int cj=0;cj<2;++cj){
    int c = cj*256+tid;
    const float4* wp = (const float4*)(Wq + (size_t)c*512);
    const float4* xp = (const float4*)xr;
    float a=0.f;
    for (int u=0;u<128;++u){
      float4 wv = wp[u], xv = xp[u];
      a += wv.x*xv.x + wv.y*xv.y + wv.z*xv.z + wv.w*xv.w;
    }
    qraw[t*512+c]=a;
  }
}

// ---------- q BN + fold kv-BN (inline from s2 stats) -> Qh bf16, cQ ----------
__global__ __launch_bounds__(512) void q_bn_qh(const float* __restrict__ qraw,
                                               const float* __restrict__ g, const float* __restrict__ bb,
                                               const float* __restrict__ s2sum, const float* __restrict__ s2sq,
                                               const float* __restrict__ g_kv, const float* __restrict__ b_kv,
                                               ushort* __restrict__ Qh, float* __restrict__ cQ)
{
  const int c = threadIdx.x;
  const int h = c >> 6, d = c & 63;
  float s=0.f,q=0.f;
  for (int t=0;t<60;++t){ float v = qraw[t*512+c]; s+=v; q+=v*v; }
  float mu=s*(1.f/60.f), var=q*(1.f/60.f)-mu*mu;
  float k = g[c]*rsqrtf(var+1e-5f);
  float sh = bb[c]-mu*k;
  const float invn = 1.f/73728.f;
  float mu2 = s2sum[h*192+d]*invn;
  float var2 = s2sq[h*192+d]*invn - mu2*mu2;
  float k2 = g_kv[h*192+d]*rsqrtf(var2+1e-5f);
  const float sk = k2*0.125f;
  const float tk = (b_kv[h*192+d]-mu2*k2)*0.125f;
  for (int t=0;t<60;++t){
    float qv = qraw[t*512+c]*k+sh;
    Qh[(h*64+t)*64+d] = f2b(qv*sk);
    float contrib = qv*tk;
    #pragma unroll
    for (int o=32;o>0;o>>=1) contrib += __shfl_xor(contrib,o);
    if (d==0) cQ[h*64+t] = contrib;
  }
  for (int t=60;t<64;++t) Qh[(h*64+t)*64+d] = 0;
  if (d==0) for (int t=60;t<64;++t) cQ[h*64+t] = 0.f;
}

// ---------- flash attention over 576-col chunk (grid 16x8x8 = 1024 blocks, 4/CU), defer-rescale ----------
__global__ __launch_bounds__(256) void attn_flash(
    const ushort* __restrict__ Qh, const float* __restrict__ cQ,
    const ushort* __restrict__ Kbuf, const ushort* __restrict__ Vt,
    const float* __restrict__ biases,
    float* __restrict__ Op, float* __restrict__ Mp, float* __restrict__ Lp)
{
  __shared__ __align__(16) ushort Qs[64*72];
  __shared__ __align__(16) ushort vt[128*64];
  __shared__ __align__(16) ushort Pw[4][16*72];
  __shared__ float bias_l[600];
  __shared__ float cQs[64];
  const int tid = threadIdx.x;
  const int l = tid & 63, w = tid >> 6;
  const int lr = l & 15, lk = l >> 4;
  const int nc = blockIdx.x, h = blockIdx.y, b = blockIdx.z;
  const int bh = b*8+h;
  const int wbase = tid & ~63;
  for (int cid = tid; cid < 512; cid += 256){
    int row = cid >> 3, c8 = cid & 7;
    *(uint4*)&Qs[row*72 + c8*8] = *(const uint4*)&Qh[(size_t)(h*64+row)*64 + c8*8];
  }
  for (int i = tid; i < 600; i += 256) bias_l[i] = biases[h*10000 + nc*600 + i];
  if (tid < 64) cQs[tid] = cQ[h*64 + tid];

  const ushort* vsrc0 = Vt + (size_t)bh*128*9216 + nc*576;
  const ushort* vsrc[4]; ushort* vdst[4];
  #pragma unroll
  for (int it=0; it<4; ++it){
    int idx = it*256 + tid;
    int row = idx >> 3, c8 = idx & 7;
    int sc8 = c8 ^ (row & 7);
    vsrc[it] = vsrc0 + (size_t)row*9216 + sc8*8;
    vdst[it] = &vt[(it*256 + wbase)*8];
  }
  const int swz = (lr & 7) << 3;
  const ushort* vp0 = &vt[lr*64 + ((lk*8) ^ swz)];
  const ushort* vp1 = &vt[lr*64 + ((lk*8) ^ swz ^ 32)];
  const ushort* kchunk = Kbuf + (size_t)b*9216*512 + h*64;
  const ushort* qsp = &Qs[(w*16+lr)*72 + lk*8];
  const ushort* pwp = &Pw[w][lr*72 + lk*8];

  float m_run[4] = {-1e30f,-1e30f,-1e30f,-1e30f};
  float l_run[4] = {0.f,0.f,0.f,0.f};
  f32x4 acc_o[8];
  #pragma unroll
  for (int j=0;j<8;++j) acc_o[j] = (f32x4){0.f,0.f,0.f,0.f};
  __syncthreads();

  for (int tile=0; tile<9; ++tile){
    const int n0 = nc*576 + tile*64;
    if (tile) __syncthreads();
    #pragma unroll
    for (int it=0; it<4; ++it) gll16(vsrc[it] + tile*64, vdst[it]);
    __syncthreads();
    f32x4 sa[4];
    #pragma unroll
    for (int j=0;j<4;++j) sa[j]=(f32x4){0.f,0.f,0.f,0.f};
    const ushort* kbase = kchunk + (size_t)n0*512;
    __builtin_amdgcn_s_setprio(1);
    #pragma unroll
    for (int kk=0; kk<64; kk+=32){
      bf16x8 af = *(const bf16x8*)(qsp + kk);
      #pragma unroll
      for (int j=0;j<4;++j){
        bf16x8 bf_ = *(const bf16x8*)&kbase[(size_t)(j*16+lr)*512 + kk + lk*8];
        sa[j] = __builtin_amdgcn_mfma_f32_16x16x32_bf16(af, bf_, sa[j], 0,0,0);
      }
    }
    __builtin_amdgcn_s_setprio(0);
    float mt[4] = {-1e30f,-1e30f,-1e30f,-1e30f};
    #pragma unroll
    for (int j=0;j<4;++j){
      int n = n0 + j*16 + lr;
      int py = n/96;
      int px = n - py*96;
      int pyl = py - nc*6;
      #pragma unroll
      for (int r=0;r<4;++r){
        int t = w*16 + lk*4 + r;
        int dd = t - px; dd = dd<0?-dd:dd;
        float s = sa[j][r] + cQs[t] + bias_l[pyl*100 + dd];
        sa[j][r] = s;
        mt[r] = fmaxf(mt[r], s);
      }
    }
    bool ok = true;
    #pragma unroll
    for (int r=0;r<4;++r){
      #pragma unroll
      for (int o=1;o<16;o<<=1) mt[r] = fmaxf(mt[r], __shfl_xor(mt[r], o));
      ok = ok && (mt[r] <= m_run[r] + 8.f);
    }
    if (!__all(ok)){
      #pragma unroll
      for (int r=0;r<4;++r){
        float mnew = fmaxf(m_run[r], mt[r]);
        float ef = __expf(m_run[r] - mnew);
        m_run[r] = mnew;
        l_run[r] *= ef;
        #pragma unroll
        for (int j2=0;j2<8;++j2) acc_o[j2][r] *= ef;
      }
    }
    float rs[4] = {0.f,0.f,0.f,0.f};
    #pragma unroll
    for (int j=0;j<4;++j)
      #pragma unroll
      for (int r=0;r<4;++r){
        float pe = __expf(sa[j][r] - m_run[r]);
        rs[r] += pe;
        Pw[w][(lk*4+r)*72 + j*16 + lr] = f2b(pe);
      }
    #pragma unroll
    for (int r=0;r<4;++r){
      #pragma unroll
      for (int o=1;o<16;o<<=1) rs[r] += __shfl_xor(rs[r], o);
      l_run[r] += rs[r];
    }
    __builtin_amdgcn_s_setprio(1);
    #pragma unroll
    for (int kk=0; kk<2; ++kk){
      bf16x8 pa = *(const bf16x8*)(pwp + kk*32);
      const ushort* vp = kk ? vp1 : vp0;
      #pragma unroll
      for (int j2=0;j2<8;++j2){
        bf16x8 vb = *(const bf16x8*)(vp + j2*1024);
        acc_o[j2] = __builtin_amdgcn_mfma_f32_16x16x32_bf16(pa, vb, acc_o[j2], 0,0,0);
      }
    }
    __builtin_amdgcn_s_setprio(0);
  }
  float* ob = Op + (((size_t)nc*64 + bh)*64)*128;
  #pragma unroll
  for (int j2=0;j2<8;++j2)
    #pragma unroll
    for (int r=0;r<4;++r){
      int row = w*16 + lk*4 + r;
      ob[(size_t)row*128 + j2*16 + lr] = acc_o[j2][r];
    }
  if (lr == 0){
    #pragma unroll
    for (int r=0;r<4;++r){
      int row = w*16 + lk*4 + r;
      Mp[(nc*64+bh)*64 + row] = m_run[r];
      Lp[(nc*64+bh)*64 + row] = l_run[r];
    }
  }
}

// ---------- row GEMM, 8 rows/block, col-split grid.y, inline input-BN, fused output stats ----------
// MODE 2: BN+hswish; 4: textd = text + BN(X); 5: fused attn-combine + attn-BN + hswish
template<int CIN, int COUT, int MODE>
__global__ __launch_bounds__(256) void rowgemm8(
    const float* __restrict__ X, const float* __restrict__ Wt,
    const float* __restrict__ isum, const float* __restrict__ isq,
    const float* __restrict__ ig, const float* __restrict__ ib, float invn,
    const float* __restrict__ text, float* __restrict__ textd,
    const float* __restrict__ Op5, const float* __restrict__ Mp5, const float* __restrict__ Lp5,
    float* __restrict__ out, float* __restrict__ osum, float* __restrict__ osq)
{
  __shared__ __align__(16) float xr[8][CIN];
  __shared__ float scf[CIN], shf[CIN];
  __shared__ float eW[8][8][16];
  __shared__ float invl[8][8];
  __shared__ int   baseRT[8][8];
  const int rb0 = blockIdx.x*8, tid = threadIdx.x;
  for (int i=tid; i<CIN; i+=256){
    int idx = (MODE==5) ? (64 + (i&127) + (i>>7)*192) : i;
    float mu = isum[idx]*invn;
    float var = isq[idx]*invn - mu*mu;
    float k = ig[idx]*rsqrtf(var+1e-5f);
    scf[i]=k; shf[i]=ib[idx]-mu*k;
  }
  if constexpr (MODE==5){
    if (tid < 64){
      int rr = tid >> 3, hh = tid & 7;
      int row = rb0 + rr;
      int bq = row / 60;
      int t  = row - bq*60;
      int bh = bq*8 + hh;
      float mv[16], mg = -1e30f;
      #pragma unroll
      for (int i=0;i<16;++i){ mv[i] = Mp5[(i*64+bh)*64 + t]; mg = fmaxf(mg, mv[i]); }
      float ls = 0.f;
      #pragma unroll
      for (int i=0;i<16;++i){
        float e = __expf(mv[i]-mg);
        eW[rr][hh][i] = e;
        ls += Lp5[(i*64+bh)*64 + t]*e;
      }
      invl[rr][hh] = 1.f/ls;
      baseRT[rr][hh] = (bh*64 + t)*128;
    }
  }
  __syncthreads();
  for (int i=tid; i<8*CIN; i+=256){
    int rr = i / CIN, cc = i % CIN;
    float v;
    if constexpr (MODE==5){
      int hh = cc >> 7, dv = cc & 127;
      const float* op = Op5 + baseRT[rr][hh] + dv;
      float o = 0.f;
      #pragma unroll
      for (int q=0;q<16;++q) o += op[(size_t)q*524288] * eW[rr][hh][q];
      v = o * invl[rr][hh];
      v = v*scf[cc] + shf[cc];
      v = hswish(v);
    } else {
      v = X[(size_t)(rb0+rr)*CIN + cc];
      v = v*scf[cc] + shf[cc];
      if constexpr (MODE==2) v = hswish(v);
      if constexpr (MODE==4){
        int t = (rb0+rr) % 60;
        v = text[t*CIN+cc] + v;
        if (blockIdx.y == 0) textd[(size_t)(rb0+rr)*CIN + cc] = v;
      }
    }
    xr[rr][cc]=v;
  }
  __syncthreads();
  int c = blockIdx.y*256 + tid;
  const float4* wp = (const float4*)(Wt + (size_t)c*CIN);
  float a[8] = {0.f,0.f,0.f,0.f,0.f,0.f,0.f,0.f};
  for (int u=0;u<CIN/4;++u){
    float4 wv = wp[u];
    #pragma unroll
    for (int rr=0;rr<8;++rr){
      float4 xv = *(const float4*)&xr[rr][u*4];
      a[rr] += wv.x*xv.x + wv.y*xv.y + wv.z*xv.z + wv.w*xv.w;
    }
  }
  float ps=0.f, pq=0.f;
  #pragma unroll
  for (int rr=0;rr<8;++rr){
    out[(size_t)(rb0+rr)*COUT + c] = a[rr];
    ps += a[rr]; pq += a[rr]*a[rr];
  }
  atomicAdd(&osum[c], ps);
  atomicAdd(&osq [c], pq);
}

// ---------- final: out = BN(f2_raw)(inline) + textd ----------
__global__ void final_out(const float* __restrict__ f2raw,
                          const float* __restrict__ ssum, const float* __restrict__ ssq,
                          const float* __restrict__ g, const float* __restrict__ bb,
                          const float* __restrict__ textd, float* __restrict__ outp)
{
  int i = blockIdx.x*256+threadIdx.x;
  if (i < 60*512){
    int c = i & 511;
    float mu = ssum[c]*(1.f/480.f);
    float var = ssq[c]*(1.f/480.f) - mu*mu;
    float k = g[c]*rsqrtf(var+1e-5f);
    outp[i] = f2raw[i]*k + (bb[c]-mu*k) + textd[i];
  }
}

extern "C" void kernel_launch(void* const* d_in, const int* in_sizes, int n_in,
                              void* d_out, int out_size, void* d_ws, size_t ws_size,
                              hipStream_t stream)
{
  (void)in_sizes; (void)n_in; (void)out_size; (void)ws_size;
  const float* im    = (const float*)d_in[0];
  const float* text  = (const float*)d_in[1];
  const float* W_dc  = (const float*)d_in[2];
  const float* g_dc  = (const float*)d_in[3];
  const float* b_dc  = (const float*)d_in[4];
  const float* W_kv  = (const float*)d_in[5];
  const float* g_kv  = (const float*)d_in[6];
  const float* b_kv  = (const float*)d_in[7];
  const float* W_q   = (const float*)d_in[8];
  const float* g_q   = (const float*)d_in[9];
  const float* b_q   = (const float*)d_in[10];
  const float* W_proj= (const float*)d_in[11];
  const float* g_proj= (const float*)d_in[12];
  const float* b_proj= (const float*)d_in[13];
  const float* biases= (const float*)d_in[14];
  const float* W_f1  = (const float*)d_in[15];
  const float* g_f1  = (const float*)d_in[16];
  const float* b_f1  = (const float*)d_in[17];
  const float* W_f2  = (const float*)d_in[18];
  const float* g_f2  = (const float*)d_in[19];
  const float* b_f2  = (const float*)d_in[20];
  float* outp = (float*)d_out;

  char* p = (char*)d_ws;
  auto alloc = [&](size_t bytes)->char*{ char* r = p; p += (bytes+255)&~(size_t)255; return r; };
  // zero zone (contiguous, 8192 floats)
  float* s1_sum = (float*)alloc(512*4);
  float* s1_sq  = (float*)alloc(512*4);
  float* s2_sum = (float*)alloc(1536*4);
  float* s2_sq  = (float*)alloc(1536*4);
  float* s3_sum = (float*)alloc(512*4);
  float* s3_sq  = (float*)alloc(512*4);
  float* s4_sum = (float*)alloc(1024*4);
  float* s4_sq  = (float*)alloc(1024*4);
  float* s5_sum = (float*)alloc(512*4);
  float* s5_sq  = (float*)alloc(512*4);
  float* zero_base = s1_sum;
  // rest
  float* qraw = (float*)alloc(60*512*4);
  ushort* Qh = (ushort*)alloc((size_t)8*64*64*2);
  float* cQ = (float*)alloc(512*4);
  float* proj_raw = (float*)alloc((size_t)480*512*4);
  float* textd=(float*)alloc((size_t)480*512*4);
  float* f1_raw=(float*)alloc((size_t)480*1024*4);
  float* f2_raw=(float*)alloc((size_t)480*512*4);
  float* Op = (float*)alloc((size_t)16*64*64*128*4);
  float* Mp = (float*)alloc((size_t)16*64*64*4);
  float* Lp = (float*)alloc((size_t)16*64*64*4);
  ushort* Wdc_b = (ushort*)alloc((size_t)512*1024*2);
  ushort* Wkv_b = (ushort*)alloc((size_t)1536*512*2);
  ushort* y1 = (ushort*)alloc((size_t)73728*512*2);
  ushort* Kbuf = (ushort*)alloc((size_t)73728*512*2);
  ushort* Vt  = (ushort*)alloc((size_t)64*128*9216*2);
  ushort* At = (ushort*)alloc((size_t)73728*1024*2);

  init_kernel<<<1024,256,0,stream>>>(W_dc, W_kv, Wdc_b, Wkv_b, zero_base);
  transpose_kernel<<<dim3(144,16,8),256,0,stream>>>(im, At);
  gemm_bt<0,4,512,1024><<<2304,512,0,stream>>>(At, Wdc_b, y1, nullptr, s1_sum, s1_sq);
  bn_hswish<<<2048,256,0,stream>>>(y1, s1_sum, s1_sq, g_dc, b_dc);
  gemm_bt<1,12,1536,512><<<6912,512,0,stream>>>(y1, Wkv_b, Kbuf, Vt, s2_sum, s2_sq);
  q_gemm<<<60,256,0,stream>>>(text, W_q, qraw);
  q_bn_qh<<<1,512,0,stream>>>(qraw, g_q, b_q, s2_sum, s2_sq, g_kv, b_kv, Qh, cQ);
  attn_flash<<<dim3(16,8,8),256,0,stream>>>(Qh, cQ, Kbuf, Vt, biases, Op, Mp, Lp);
  rowgemm8<1024,512,5><<<dim3(60,2),256,0,stream>>>(nullptr, W_proj, s2_sum, s2_sq, g_kv, b_kv, 1.f/73728.f,
                                                    nullptr, nullptr, Op, Mp, Lp, proj_raw, s3_sum, s3_sq);
  rowgemm8<512,1024,4><<<dim3(60,4),256,0,stream>>>(proj_raw, W_f1, s3_sum, s3_sq, g_proj, b_proj, 1.f/480.f,
                                                    text, textd, nullptr, nullptr, nullptr, f1_raw, s4_sum, s4_sq);
  rowgemm8<1024,512,2><<<dim3(60,2),256,0,stream>>>(f1_raw, W_f2, s4_sum, s4_sq, g_f1, b_f1, 1.f/480.f,
                                                    nullptr, nullptr, nullptr, nullptr, nullptr, f2_raw, s5_sum, s5_sq);
  final_out<<<120,256,0,stream>>>(f2_raw, s5_sum, s5_sq, g_f2, b_f2, textd, outp);
}

// Round 17
// 702.603 us; speedup vs baseline: 1.0058x; 1.0058x over previous
//
#include <hip/hip_runtime.h>
#include <hip/hip_bf16.h>
#include <stdint.h>

typedef short bf16x8 __attribute__((ext_vector_type(8)));
typedef float f32x4 __attribute__((ext_vector_type(4)));

__device__ __forceinline__ float b2f(ushort u){ return __uint_as_float(((uint32_t)u)<<16); }
__device__ __forceinline__ ushort f2b(float f){
  uint32_t u = __float_as_uint(f);
  u += 0x7fffu + ((u>>16)&1u);
  return (ushort)(u>>16);
}
__device__ __forceinline__ float hswish(float x){ return x*fminf(fmaxf(x+3.f,0.f),6.f)*(1.f/6.f); }

// async global->LDS 16B (dest = wave-uniform base + lane*16)
__device__ __forceinline__ void gll16(const void* g, void* l){
  __builtin_amdgcn_global_load_lds((const __attribute__((address_space(1))) void*)g,
                                   (__attribute__((address_space(3))) void*)l, 16, 0, 0);
}

// ---------- init: zero stats accumulators + convert weights to bf16 ----------
__global__ void init_kernel(const float* __restrict__ Wdc, const float* __restrict__ Wkv,
                            ushort* __restrict__ Wdc_b, ushort* __restrict__ Wkv_b,
                            float* __restrict__ zbase){
  int i = blockIdx.x*256 + threadIdx.x;
  if (i < 8192) zbase[i] = 0.f;
  for (int j=i; j<512*1024; j+=262144) Wdc_b[j] = f2b(Wdc[j]);
  for (int j=i; j<1536*512; j+=262144) Wkv_b[j] = f2b(Wkv[j]);
}

// ---------- transpose im_emd (B,C,N) f32 -> At[(b*N+n)][c] bf16 ----------
__global__ __launch_bounds__(256) void transpose_kernel(const float* __restrict__ im, ushort* __restrict__ At){
  __shared__ float tb[64][65];
  const int b = blockIdx.z, c0 = blockIdx.y*64, n0 = blockIdx.x*64;
  const int tid = threadIdx.x;
  const int cl = tid >> 2, q = tid & 3;
  #pragma unroll
  for (int it=0; it<4; ++it){
    int nn = q*4 + it*16;
    float4 v = *(const float4*)&im[((size_t)(b*1024 + c0 + cl))*9216 + n0 + nn];
    tb[cl][nn+0]=v.x; tb[cl][nn+1]=v.y; tb[cl][nn+2]=v.z; tb[cl][nn+3]=v.w;
  }
  __syncthreads();
  const int nr = tid >> 4, c4 = (tid & 15)*4;
  #pragma unroll
  for (int ps=0; ps<4; ++ps){
    int nn = nr + ps*16;
    ushort4 u;
    u.x = f2b(tb[c4+0][nn]); u.y = f2b(tb[c4+1][nn]);
    u.z = f2b(tb[c4+2][nn]); u.w = f2b(tb[c4+3][nn]);
    *(ushort4*)&At[((size_t)(b*9216 + n0 + nn))*1024 + c0 + c4] = u;
  }
}

// ---------- MFMA GEMM 128x128, 256 thr, fused column stats, compile-time shape ----------
// SPLIT=0: C -> Cm[m][N].  SPLIT=1 (kv): K cols -> Kbuf[b][n][h][64], V cols -> Vt[b][h][dv][9216]
template<int SPLIT, int NT, int N, int K>
__global__ __launch_bounds__(256) void gemm_bt(
    const ushort* __restrict__ A, const ushort* __restrict__ Bm,
    ushort* __restrict__ Cm, ushort* __restrict__ Vt,
    float* __restrict__ sums, float* __restrict__ sqs)
{
  __shared__ __align__(16) ushort As[128*64];
  __shared__ __align__(16) ushort Bs[128*64];
  const int tid = threadIdx.x;
  const int l = tid & 63;
  const int w = tid >> 6;
  const int wm = w >> 1, wn = w & 1;
  const int chunk = gridDim.x >> 3;
  const int wg = (blockIdx.x & 7)*chunk + (blockIdx.x >> 3);
  const int tn = wg % NT, tm = wg / NT;
  const size_t n0 = (size_t)tn * 128;
  const size_t m0 = (size_t)tm * 128;
  const int lr = l & 15, lk = l >> 4;
  const int wbase = tid & ~63;

  const ushort* asrc[4]; const ushort* bsrc[4]; ushort* adst[4]; ushort* bdst[4];
  #pragma unroll
  for (int it=0; it<4; ++it){
    int idx = it*256 + tid;
    int row = idx >> 3, c8 = idx & 7;
    int sc8 = c8 ^ (row & 7);
    asrc[it] = A  + (m0+row)*K + sc8*8;
    bsrc[it] = Bm + (n0+row)*K + sc8*8;
    adst[it] = &As[(it*256 + wbase)*8];
    bdst[it] = &Bs[(it*256 + wbase)*8];
  }
  const int swz = (lr & 7) << 3;
  const ushort* ap0 = &As[(wm*64 + lr)*64 + ((lk*8) ^ swz)];
  const ushort* ap1 = &As[(wm*64 + lr)*64 + ((lk*8) ^ swz ^ 32)];
  const ushort* bp0 = &Bs[(wn*64 + lr)*64 + ((lk*8) ^ swz)];
  const ushort* bp1 = &Bs[(wn*64 + lr)*64 + ((lk*8) ^ swz ^ 32)];

  f32x4 acc[4][4];
  #pragma unroll
  for (int i=0;i<4;++i)
    #pragma unroll
    for (int j=0;j<4;++j) acc[i][j] = (f32x4){0.f,0.f,0.f,0.f};

  #pragma unroll
  for (int kt = 0; kt < K; kt += 64) {
    #pragma unroll
    for (int it=0; it<4; ++it) {
      gll16(asrc[it] + kt, adst[it]);
      gll16(bsrc[it] + kt, bdst[it]);
    }
    __syncthreads();
    #pragma unroll
    for (int kk=0; kk<2; ++kk) {
      const ushort* ap = kk ? ap1 : ap0;
      const ushort* bp = kk ? bp1 : bp0;
      bf16x8 af[4], bfr[4];
      #pragma unroll
      for (int i=0;i<4;++i) af[i]  = *(const bf16x8*)(ap + i*1024);
      #pragma unroll
      for (int j=0;j<4;++j) bfr[j] = *(const bf16x8*)(bp + j*1024);
      #pragma unroll
      for (int i=0;i<4;++i)
        #pragma unroll
        for (int j=0;j<4;++j)
          acc[i][j] = __builtin_amdgcn_mfma_f32_16x16x32_bf16(af[i], bfr[j], acc[i][j], 0, 0, 0);
    }
    __syncthreads();
  }
  if constexpr (SPLIT==0){
    #pragma unroll
    for (int i=0;i<4;++i)
      #pragma unroll
      for (int j=0;j<4;++j)
        #pragma unroll
        for (int r=0;r<4;++r) {
          size_t row = m0 + wm*64 + i*16 + lk*4 + r;
          size_t col = n0 + wn*64 + j*16 + lr;
          Cm[row*N + col] = f2b(acc[i][j][r]);
        }
  } else {
    const int bq = (int)(m0/9216);
    const int nbase = (int)(m0 - (size_t)bq*9216);
    #pragma unroll
    for (int j=0;j<4;++j){
      int c = (int)n0 + wn*64 + j*16 + lr;
      int h = c/192, rcol = c - h*192;
      #pragma unroll
      for (int i=0;i<4;++i){
        int nrow = nbase + wm*64 + i*16 + lk*4;
        if (rcol < 64){
          ushort* kb = Cm + ((size_t)(bq*9216 + nrow))*512 + h*64 + rcol;
          #pragma unroll
          for (int r=0;r<4;++r) kb[(size_t)r*512] = f2b(acc[i][j][r]);
        } else {
          int dv = rcol - 64;
          ushort4 u;
          u.x=f2b(acc[i][j][0]); u.y=f2b(acc[i][j][1]);
          u.z=f2b(acc[i][j][2]); u.w=f2b(acc[i][j][3]);
          *(ushort4*)&Vt[((size_t)((bq*8+h)*128 + dv))*9216 + nrow] = u;
        }
      }
    }
  }
  #pragma unroll
  for (int j=0;j<4;++j){
    float cs=0.f, cq=0.f;
    #pragma unroll
    for (int i=0;i<4;++i)
      #pragma unroll
      for (int r=0;r<4;++r){ float v=acc[i][j][r]; cs+=v; cq+=v*v; }
    cs += __shfl_xor(cs,16); cs += __shfl_xor(cs,32);
    cq += __shfl_xor(cq,16); cq += __shfl_xor(cq,32);
    if (lk==0){
      int col = (int)n0 + wn*64 + j*16 + lr;
      atomicAdd(&sums[col], cs);
      atomicAdd(&sqs [col], cq);
    }
  }
}

// ---------- BN(inline finalize) + hardswish in place on y1 ----------
__global__ __launch_bounds__(256) void bn_hswish(ushort* __restrict__ y,
    const float* __restrict__ ssum, const float* __restrict__ ssq,
    const float* __restrict__ g, const float* __restrict__ bb)
{
  __shared__ float sc[512], sh[512];
  const float invn = 1.f/73728.f;
  for (int i=threadIdx.x;i<512;i+=256){
    float mu = ssum[i]*invn;
    float var = ssq[i]*invn - mu*mu;
    float k = g[i]*rsqrtf(var+1e-5f);
    sc[i]=k; sh[i]=bb[i]-mu*k;
  }
  __syncthreads();
  const size_t total = (size_t)73728*512/8;
  for (size_t idx = (size_t)blockIdx.x*256+threadIdx.x; idx < total; idx += (size_t)gridDim.x*256){
    uint4 u = *(uint4*)&y[idx*8];
    ushort* up = (ushort*)&u;
    int c0 = ((int)(idx & 63))*8;
    #pragma unroll
    for (int e=0;e<8;++e){
      float x = b2f(up[e])*sc[c0+e] + sh[c0+e];
      up[e] = f2b(hswish(x));
    }
    *(uint4*)&y[idx*8] = u;
  }
}

// ---------- q = text @ Wq^T (raw, f32), one text-row per block ----------
__global__ __launch_bounds__(256) void q_gemm(const float* __restrict__ text, const float* __restrict__ Wq, float* __restrict__ qraw)
{
  __shared__ __align__(16) float xr[512];
  const int t = blockIdx.x, tid = threadIdx.x;
  for (int i=tid;i<512;i+=256) xr[i] = text[t*512+i];
  __syncthreads();
  #pragma unroll
  for (int cj=0;cj<2;++cj){
    int c = cj*256+tid;
    const float4* wp = (const float4*)(Wq + (size_t)c*512);
    const float4* xp = (const float4*)xr;
    float a=0.f;
    for (int u=0;u<128;++u){
      float4 wv = wp[u], xv = xp[u];
      a += wv.x*xv.x + wv.y*xv.y + wv.z*xv.z + wv.w*xv.w;
    }
    qraw[t*512+c]=a;
  }
}

// ---------- q BN + fold kv-BN (inline from s2 stats) -> Qh bf16, cQ ----------
__global__ __launch_bounds__(512) void q_bn_qh(const float* __restrict__ qraw,
                                               const float* __restrict__ g, const float* __restrict__ bb,
                                               const float* __restrict__ s2sum, const float* __restrict__ s2sq,
                                               const float* __restrict__ g_kv, const float* __restrict__ b_kv,
                                               ushort* __restrict__ Qh, float* __restrict__ cQ)
{
  const int c = threadIdx.x;
  const int h = c >> 6, d = c & 63;
  float s=0.f,q=0.f;
  for (int t=0;t<60;++t){ float v = qraw[t*512+c]; s+=v; q+=v*v; }
  float mu=s*(1.f/60.f), var=q*(1.f/60.f)-mu*mu;
  float k = g[c]*rsqrtf(var+1e-5f);
  float sh = bb[c]-mu*k;
  const float invn = 1.f/73728.f;
  float mu2 = s2sum[h*192+d]*invn;
  float var2 = s2sq[h*192+d]*invn - mu2*mu2;
  float k2 = g_kv[h*192+d]*rsqrtf(var2+1e-5f);
  const float sk = k2*0.125f;
  const float tk = (b_kv[h*192+d]-mu2*k2)*0.125f;
  for (int t=0;t<60;++t){
    float qv = qraw[t*512+c]*k+sh;
    Qh[(h*64+t)*64+d] = f2b(qv*sk);
    float contrib = qv*tk;
    #pragma unroll
    for (int o=32;o>0;o>>=1) contrib += __shfl_xor(contrib,o);
    if (d==0) cQ[h*64+t] = contrib;
  }
  for (int t=60;t<64;++t) Qh[(h*64+t)*64+d] = 0;
  if (d==0) for (int t=60;t<64;++t) cQ[h*64+t] = 0.f;
}

// ---------- flash attention over 576-col chunk (grid 16x8x8 = 1024 blocks, 4/CU), defer-rescale ----------
__global__ __launch_bounds__(256) void attn_flash(
    const ushort* __restrict__ Qh, const float* __restrict__ cQ,
    const ushort* __restrict__ Kbuf, const ushort* __restrict__ Vt,
    const float* __restrict__ biases,
    float* __restrict__ Op, float* __restrict__ Mp, float* __restrict__ Lp)
{
  __shared__ __align__(16) ushort Qs[64*72];
  __shared__ __align__(16) ushort vt[128*64];
  __shared__ __align__(16) ushort Pw[4][16*72];
  __shared__ float bias_l[600];
  __shared__ float cQs[64];
  const int tid = threadIdx.x;
  const int l = tid & 63, w = tid >> 6;
  const int lr = l & 15, lk = l >> 4;
  const int nc = blockIdx.x, h = blockIdx.y, b = blockIdx.z;
  const int bh = b*8+h;
  const int wbase = tid & ~63;
  for (int cid = tid; cid < 512; cid += 256){
    int row = cid >> 3, c8 = cid & 7;
    *(uint4*)&Qs[row*72 + c8*8] = *(const uint4*)&Qh[(size_t)(h*64+row)*64 + c8*8];
  }
  for (int i = tid; i < 600; i += 256) bias_l[i] = biases[h*10000 + nc*600 + i];
  if (tid < 64) cQs[tid] = cQ[h*64 + tid];

  const ushort* vsrc0 = Vt + (size_t)bh*128*9216 + nc*576;
  const ushort* vsrc[4]; ushort* vdst[4];
  #pragma unroll
  for (int it=0; it<4; ++it){
    int idx = it*256 + tid;
    int row = idx >> 3, c8 = idx & 7;
    int sc8 = c8 ^ (row & 7);
    vsrc[it] = vsrc0 + (size_t)row*9216 + sc8*8;
    vdst[it] = &vt[(it*256 + wbase)*8];
  }
  const int swz = (lr & 7) << 3;
  const ushort* vp0 = &vt[lr*64 + ((lk*8) ^ swz)];
  const ushort* vp1 = &vt[lr*64 + ((lk*8) ^ swz ^ 32)];
  const ushort* kchunk = Kbuf + (size_t)b*9216*512 + h*64;
  const ushort* qsp = &Qs[(w*16+lr)*72 + lk*8];
  const ushort* pwp = &Pw[w][lr*72 + lk*8];

  float m_run[4] = {-1e30f,-1e30f,-1e30f,-1e30f};
  float l_run[4] = {0.f,0.f,0.f,0.f};
  f32x4 acc_o[8];
  #pragma unroll
  for (int j=0;j<8;++j) acc_o[j] = (f32x4){0.f,0.f,0.f,0.f};
  __syncthreads();

  for (int tile=0; tile<9; ++tile){
    const int n0 = nc*576 + tile*64;
    if (tile) __syncthreads();
    #pragma unroll
    for (int it=0; it<4; ++it) gll16(vsrc[it] + tile*64, vdst[it]);
    __syncthreads();
    f32x4 sa[4];
    #pragma unroll
    for (int j=0;j<4;++j) sa[j]=(f32x4){0.f,0.f,0.f,0.f};
    const ushort* kbase = kchunk + (size_t)n0*512;
    __builtin_amdgcn_s_setprio(1);
    #pragma unroll
    for (int kk=0; kk<64; kk+=32){
      bf16x8 af = *(const bf16x8*)(qsp + kk);
      #pragma unroll
      for (int j=0;j<4;++j){
        bf16x8 bf_ = *(const bf16x8*)&kbase[(size_t)(j*16+lr)*512 + kk + lk*8];
        sa[j] = __builtin_amdgcn_mfma_f32_16x16x32_bf16(af, bf_, sa[j], 0,0,0);
      }
    }
    __builtin_amdgcn_s_setprio(0);
    float mt[4] = {-1e30f,-1e30f,-1e30f,-1e30f};
    #pragma unroll
    for (int j=0;j<4;++j){
      int n = n0 + j*16 + lr;
      int py = n/96;
      int px = n - py*96;
      int pyl = py - nc*6;
      #pragma unroll
      for (int r=0;r<4;++r){
        int t = w*16 + lk*4 + r;
        int dd = t - px; dd = dd<0?-dd:dd;
        float s = sa[j][r] + cQs[t] + bias_l[pyl*100 + dd];
        sa[j][r] = s;
        mt[r] = fmaxf(mt[r], s);
      }
    }
    bool ok = true;
    #pragma unroll
    for (int r=0;r<4;++r){
      #pragma unroll
      for (int o=1;o<16;o<<=1) mt[r] = fmaxf(mt[r], __shfl_xor(mt[r], o));
      ok = ok && (mt[r] <= m_run[r] + 8.f);
    }
    if (!__all(ok)){
      #pragma unroll
      for (int r=0;r<4;++r){
        float mnew = fmaxf(m_run[r], mt[r]);
        float ef = __expf(m_run[r] - mnew);
        m_run[r] = mnew;
        l_run[r] *= ef;
        #pragma unroll
        for (int j2=0;j2<8;++j2) acc_o[j2][r] *= ef;
      }
    }
    float rs[4] = {0.f,0.f,0.f,0.f};
    #pragma unroll
    for (int j=0;j<4;++j)
      #pragma unroll
      for (int r=0;r<4;++r){
        float pe = __expf(sa[j][r] - m_run[r]);
        rs[r] += pe;
        Pw[w][(lk*4+r)*72 + j*16 + lr] = f2b(pe);
      }
    #pragma unroll
    for (int r=0;r<4;++r){
      #pragma unroll
      for (int o=1;o<16;o<<=1) rs[r] += __shfl_xor(rs[r], o);
      l_run[r] += rs[r];
    }
    __builtin_amdgcn_s_setprio(1);
    #pragma unroll
    for (int kk=0; kk<2; ++kk){
      bf16x8 pa = *(const bf16x8*)(pwp + kk*32);
      const ushort* vp = kk ? vp1 : vp0;
      #pragma unroll
      for (int j2=0;j2<8;++j2){
        bf16x8 vb = *(const bf16x8*)(vp + j2*1024);
        acc_o[j2] = __builtin_amdgcn_mfma_f32_16x16x32_bf16(pa, vb, acc_o[j2], 0,0,0);
      }
    }
    __builtin_amdgcn_s_setprio(0);
  }
  float* ob = Op + (((size_t)nc*64 + bh)*64)*128;
  #pragma unroll
  for (int j2=0;j2<8;++j2)
    #pragma unroll
    for (int r=0;r<4;++r){
      int row = w*16 + lk*4 + r;
      ob[(size_t)row*128 + j2*16 + lr] = acc_o[j2][r];
    }
  if (lr == 0){
    #pragma unroll
    for (int r=0;r<4;++r){
      int row = w*16 + lk*4 + r;
      Mp[(nc*64+bh)*64 + row] = m_run[r];
      Lp[(nc*64+bh)*64 + row] = l_run[r];
    }
  }
}

// ---------- row GEMM, 8 rows/block, col-split grid.y, inline input-BN, fused output stats ----------
// MODE 2: BN+hswish; 4: textd = text + BN(X); 5: fused attn-combine + attn-BN + hswish
template<int CIN, int COUT, int MODE>
__global__ __launch_bounds__(256) void rowgemm8(
    const float* __restrict__ X, const float* __restrict__ Wt,
    const float* __restrict__ isum, const float* __restrict__ isq,
    const float* __restrict__ ig, const float* __restrict__ ib, float invn,
    const float* __restrict__ text, float* __restrict__ textd,
    const float* __restrict__ Op5, const float* __restrict__ Mp5, const float* __restrict__ Lp5,
    float* __restrict__ out, float* __restrict__ osum, float* __restrict__ osq)
{
  __shared__ __align__(16) float xr[8][CIN];
  __shared__ float scf[CIN], shf[CIN];
  __shared__ float eW[8][8][16];
  __shared__ float invl[8][8];
  __shared__ int   baseRT[8][8];
  const int rb0 = blockIdx.x*8, tid = threadIdx.x;
  for (int i=tid; i<CIN; i+=256){
    int idx = (MODE==5) ? (64 + (i&127) + (i>>7)*192) : i;
    float mu = isum[idx]*invn;
    float var = isq[idx]*invn - mu*mu;
    float k = ig[idx]*rsqrtf(var+1e-5f);
    scf[i]=k; shf[i]=ib[idx]-mu*k;
  }
  if constexpr (MODE==5){
    if (tid < 64){
      int rr = tid >> 3, hh = tid & 7;
      int row = rb0 + rr;
      int bq = row / 60;
      int t  = row - bq*60;
      int bh = bq*8 + hh;
      float mv[16], mg = -1e30f;
      #pragma unroll
      for (int i=0;i<16;++i){ mv[i] = Mp5[(i*64+bh)*64 + t]; mg = fmaxf(mg, mv[i]); }
      float ls = 0.f;
      #pragma unroll
      for (int i=0;i<16;++i){
        float e = __expf(mv[i]-mg);
        eW[rr][hh][i] = e;
        ls += Lp5[(i*64+bh)*64 + t]*e;
      }
      invl[rr][hh] = 1.f/ls;
      baseRT[rr][hh] = (bh*64 + t)*128;
    }
  }
  __syncthreads();
  for (int i=tid; i<8*CIN; i+=256){
    int rr = i / CIN, cc = i % CIN;
    float v;
    if constexpr (MODE==5){
      int hh = cc >> 7, dv = cc & 127;
      const float* op = Op5 + baseRT[rr][hh] + dv;
      float o = 0.f;
      #pragma unroll
      for (int q=0;q<16;++q) o += op[(size_t)q*524288] * eW[rr][hh][q];
      v = o * invl[rr][hh];
      v = v*scf[cc] + shf[cc];
      v = hswish(v);
    } else {
      v = X[(size_t)(rb0+rr)*CIN + cc];
      v = v*scf[cc] + shf[cc];
      if constexpr (MODE==2) v = hswish(v);
      if constexpr (MODE==4){
        int t = (rb0+rr) % 60;
        v = text[t*CIN+cc] + v;
        if (blockIdx.y == 0) textd[(size_t)(rb0+rr)*CIN + cc] = v;
      }
    }
    xr[rr][cc]=v;
  }
  __syncthreads();
  int c = blockIdx.y*256 + tid;
  const float4* wp = (const float4*)(Wt + (size_t)c*CIN);
  float a[8] = {0.f,0.f,0.f,0.f,0.f,0.f,0.f,0.f};
  for (int u=0;u<CIN/4;++u){
    float4 wv = wp[u];
    #pragma unroll
    for (int rr=0;rr<8;++rr){
      float4 xv = *(const float4*)&xr[rr][u*4];
      a[rr] += wv.x*xv.x + wv.y*xv.y + wv.z*xv.z + wv.w*xv.w;
    }
  }
  float ps=0.f, pq=0.f;
  #pragma unroll
  for (int rr=0;rr<8;++rr){
    out[(size_t)(rb0+rr)*COUT + c] = a[rr];
    ps += a[rr]; pq += a[rr]*a[rr];
  }
  atomicAdd(&osum[c], ps);
  atomicAdd(&osq [c], pq);
}

// ---------- final: out = BN(f2_raw)(inline) + textd ----------
__global__ void final_out(const float* __restrict__ f2raw,
                          const float* __restrict__ ssum, const float* __restrict__ ssq,
                          const float* __restrict__ g, const float* __restrict__ bb,
                          const float* __restrict__ textd, float* __restrict__ outp)
{
  int i = blockIdx.x*256+threadIdx.x;
  if (i < 60*512){
    int c = i & 511;
    float mu = ssum[c]*(1.f/480.f);
    float var = ssq[c]*(1.f/480.f) - mu*mu;
    float k = g[c]*rsqrtf(var+1e-5f);
    outp[i] = f2raw[i]*k + (bb[c]-mu*k) + textd[i];
  }
}

extern "C" void kernel_launch(void* const* d_in, const int* in_sizes, int n_in,
                              void* d_out, int out_size, void* d_ws, size_t ws_size,
                              hipStream_t stream)
{
  (void)in_sizes; (void)n_in; (void)out_size; (void)ws_size;
  const float* im    = (const float*)d_in[0];
  const float* text  = (const float*)d_in[1];
  const float* W_dc  = (const float*)d_in[2];
  const float* g_dc  = (const float*)d_in[3];
  const float* b_dc  = (const float*)d_in[4];
  const float* W_kv  = (const float*)d_in[5];
  const float* g_kv  = (const float*)d_in[6];
  const float* b_kv  = (const float*)d_in[7];
  const float* W_q   = (const float*)d_in[8];
  const float* g_q   = (const float*)d_in[9];
  const float* b_q   = (const float*)d_in[10];
  const float* W_proj= (const float*)d_in[11];
  const float* g_proj= (const float*)d_in[12];
  const float* b_proj= (const float*)d_in[13];
  const float* biases= (const float*)d_in[14];
  const float* W_f1  = (const float*)d_in[15];
  const float* g_f1  = (const float*)d_in[16];
  const float* b_f1  = (const float*)d_in[17];
  const float* W_f2  = (const float*)d_in[18];
  const float* g_f2  = (const float*)d_in[19];
  const float* b_f2  = (const float*)d_in[20];
  float* outp = (float*)d_out;

  char* p = (char*)d_ws;
  auto alloc = [&](size_t bytes)->char*{ char* r = p; p += (bytes+255)&~(size_t)255; return r; };
  // zero zone (contiguous, 8192 floats)
  float* s1_sum = (float*)alloc(512*4);
  float* s1_sq  = (float*)alloc(512*4);
  float* s2_sum = (float*)alloc(1536*4);
  float* s2_sq  = (float*)alloc(1536*4);
  float* s3_sum = (float*)alloc(512*4);
  float* s3_sq  = (float*)alloc(512*4);
  float* s4_sum = (float*)alloc(1024*4);
  float* s4_sq  = (float*)alloc(1024*4);
  float* s5_sum = (float*)alloc(512*4);
  float* s5_sq  = (float*)alloc(512*4);
  float* zero_base = s1_sum;
  // rest
  float* qraw = (float*)alloc(60*512*4);
  ushort* Qh = (ushort*)alloc((size_t)8*64*64*2);
  float* cQ = (float*)alloc(512*4);
  float* proj_raw = (float*)alloc((size_t)480*512*4);
  float* textd=(float*)alloc((size_t)480*512*4);
  float* f1_raw=(float*)alloc((size_t)480*1024*4);
  float* f2_raw=(float*)alloc((size_t)480*512*4);
  float* Op = (float*)alloc((size_t)16*64*64*128*4);
  float* Mp = (float*)alloc((size_t)16*64*64*4);
  float* Lp = (float*)alloc((size_t)16*64*64*4);
  ushort* Wdc_b = (ushort*)alloc((size_t)512*1024*2);
  ushort* Wkv_b = (ushort*)alloc((size_t)1536*512*2);
  ushort* y1 = (ushort*)alloc((size_t)73728*512*2);
  ushort* Kbuf = (ushort*)alloc((size_t)73728*512*2);
  ushort* Vt  = (ushort*)alloc((size_t)64*128*9216*2);
  ushort* At = (ushort*)alloc((size_t)73728*1024*2);

  init_kernel<<<1024,256,0,stream>>>(W_dc, W_kv, Wdc_b, Wkv_b, zero_base);
  transpose_kernel<<<dim3(144,16,8),256,0,stream>>>(im, At);
  gemm_bt<0,4,512,1024><<<2304,256,0,stream>>>(At, Wdc_b, y1, nullptr, s1_sum, s1_sq);
  bn_hswish<<<2048,256,0,stream>>>(y1, s1_sum, s1_sq, g_dc, b_dc);
  gemm_bt<1,12,1536,512><<<6912,256,0,stream>>>(y1, Wkv_b, Kbuf, Vt, s2_sum, s2_sq);
  q_gemm<<<60,256,0,stream>>>(text, W_q, qraw);
  q_bn_qh<<<1,512,0,stream>>>(qraw, g_q, b_q, s2_sum, s2_sq, g_kv, b_kv, Qh, cQ);
  attn_flash<<<dim3(16,8,8),256,0,stream>>>(Qh, cQ, Kbuf, Vt, biases, Op, Mp, Lp);
  rowgemm8<1024,512,5><<<dim3(60,2),256,0,stream>>>(nullptr, W_proj, s2_sum, s2_sq, g_kv, b_kv, 1.f/73728.f,
                                                    nullptr, nullptr, Op, Mp, Lp, proj_raw, s3_sum, s3_sq);
  rowgemm8<512,1024,4><<<dim3(60,4),256,0,stream>>>(proj_raw, W_f1, s3_sum, s3_sq, g_proj, b_proj, 1.f/480.f,
                                                    text, textd, nullptr, nullptr, nullptr, f1_raw, s4_sum, s4_sq);
  rowgemm8<1024,512,2><<<dim3(60,2),256,0,stream>>>(f1_raw, W_f2, s4_sum, s4_sq, g_f1, b_f1, 1.f/480.f,
                                                    nullptr, nullptr, nullptr, nullptr, nullptr, f2_raw, s5_sum, s5_sq);
  final_out<<<120,256,0,stream>>>(f2_raw, s5_sum, s5_sq, g_f2, b_f2, textd, outp);
}